// Round 8
// baseline (6169.298 us; speedup 1.0000x reference)
//
#include <hip/hip_runtime.h>

#define T_STEPS 1000
#define DT 0.1f
#define HIDDEN 128
#define N_AGENTS 1024
#define U 4
#define RING (U + 16)   // pending-accumulator slots (indices 0..U+15)

// tanh(x) = 1 - 2/(exp(2x)+1); exact at +/-inf, ~1e-7 rel error.
__device__ __forceinline__ float tanh_fast(float x) {
    float e = __expf(2.0f * x);
    return 1.0f - 2.0f * __builtin_amdgcn_rcpf(e + 1.0f);
}

// Opaque 16B load: asm results can't be remat'd/sunk into the loop
// (R6-proven: weights stay register-file-resident with zero reload traffic).
__device__ __forceinline__ float4 opaque_load16(const float* p) {
    float4 v;
    asm volatile("global_load_dwordx4 %0, %1, off\n\ts_waitcnt vmcnt(0)"
                 : "=v"(v)
                 : "v"((unsigned long long)(uintptr_t)p)
                 : "memory");
    return v;
}

// PUSH-MODEL, 4 waves/agent (R6 shell + R7 dataflow, sized to NOT spill).
//
// Wave (r,h) = (wave>>1, wave&1): lane owns row 64r+lane, ages 16h..16h+15
// -> 64 weight floats/lane (R6-proven envelope; R7's 128/lane spilled to
// scratch = 8.9 GB FETCH). Pending ring R[20]: at step t, push e(t+1) into
// R[j+1..j+16] (compile-time indices via U=4 unroll + rotate), consume R[j].
//   h=0: R[j] = own-ages partial for step t; add h=1 partial from LDS
//        (written 16 steps ago), bias, relu, layer-2 parity butterfly.
//   h=1: R[j] = partial for step t+16; ship to LDS ring part1[(t+16)&31].
// Slot reuse is 15+ barriers apart -> race-free with the 1 barrier/step.
// LDS traffic: 1 b32 read + 1 b32 write per wave-step (~150 cyc/CU-step vs
// R6's 3072 for window reads = the measured 3000-cyc bottleneck).
__global__ __launch_bounds__(256)
__attribute__((amdgpu_waves_per_eu(4, 4)))
void sim_kernel(const float* __restrict__ target_pos,
                const float* __restrict__ logsigma,
                const float* __restrict__ x_inits,
                const float* W1,
                const float* __restrict__ b1,
                const float* __restrict__ W2,
                const float* __restrict__ b2,
                float2* __restrict__ ws) {
    const int agent = blockIdx.x;
    const int tid  = threadIdx.x;   // 0..255
    const int wave = tid >> 6;      // 0..3
    const int lane = tid & 63;
    const int r    = wave >> 1;     // row-group: rows 64r+lane
    const int h    = wave & 1;      // age-half: ages 16h..16h+15
    const int row  = (r << 6) + lane;

    __shared__ float part1[2][32][64];       // h=1 -> h=0, 16-step delay
    __shared__ alignas(16) float pbf[2][4];  // [parity][r*2 + (0:p0|1:p1)]

    const float tx0 = target_pos[0], ty0 = target_pos[1];
    const float tx1 = target_pos[2], ty1 = target_pos[3];
    const float tx2 = target_pos[4], ty2 = target_pos[5];
    const float is0 = 1.0f / expf(logsigma[0]);
    const float is1 = 1.0f / expf(logsigma[1]);
    const float is2 = 1.0f / expf(logsigma[2]);

    // 48 position + 16 conc weights for (row, ages 16h..16h+15).
    float Wp[48], Wc[16];
    {
        const float* rowp = W1 + row * 128;
        #pragma unroll
        for (int i = 0; i < 12; ++i) {
            float4 v = opaque_load16(rowp + 48 * h + 4 * i);
            Wp[4*i] = v.x; Wp[4*i+1] = v.y; Wp[4*i+2] = v.z; Wp[4*i+3] = v.w;
        }
        #pragma unroll
        for (int i = 0; i < 4; ++i) {
            float4 v = opaque_load16(rowp + 96 + 16 * h + 4 * i);
            Wc[4*i] = v.x; Wc[4*i+1] = v.y; Wc[4*i+2] = v.z; Wc[4*i+3] = v.w;
        }
    }
    const float b1r   = b1[row];                      // used by h=0 only
    const float w2own = W2[(lane & 1) * HIDDEN + row];
    const float w2oth = W2[((lane & 1) ^ 1) * HIDDEN + row];
    const float b2x = b2[0], b2y = b2[1];

    float x  = x_inits[3 * agent];
    float y  = x_inits[3 * agent + 1];
    float th = x_inits[3 * agent + 2];

    auto conc = [&](float px, float py) {
        float dx0 = px - tx0, dy0 = py - ty0;
        float dx1 = px - tx1, dy1 = py - ty1;
        float dx2 = px - tx2, dy2 = py - ty2;
        float cc  = is0 * __expf(-(dx0*dx0 + dy0*dy0) * is0);
        cc       += is1 * __expf(-(dx1*dx1 + dy1*dy1) * is1);
        cc       += is2 * __expf(-(dx2*dx2 + dy2*dy2) * is2);
        return cc;
    };

    float c = conc(x, y);

    // Seed: history pre-filled with e(0). R[j] = sum_{k=j..15} Wloc[k].e(0).
    float R[RING];
    #pragma unroll
    for (int i = 16; i < RING; ++i) R[i] = 0.f;
    {
        float acc = 0.f;
        #pragma unroll
        for (int k = 15; k >= 0; --k) {
            acc = fmaf(Wp[3*k], x,
                   fmaf(Wp[3*k+1], y,
                    fmaf(Wp[3*k+2], th,
                     fmaf(Wc[k], c, acc))));
            R[k] = acc;
        }
    }
    // h=1 partials for steps 0..15 are all the full e(0) sum = R[0].
    if (h == 1) {
        #pragma unroll
        for (int s = 0; s < 16; ++s) part1[r][s][lane] = R[0];
    }
    __syncthreads();

    float S_c = 0.f, S_u = 0.f;
    int t = 0;

    #pragma unroll 1
    for (int tt = 0; tt < T_STEPS / U; ++tt) {
        #pragma unroll
        for (int j = 0; j < U; ++j, ++t) {
            // ---- consume / ship (wave-uniform branch, no divergence) ----
            if (h == 0) {
                float hv = fmaxf(R[j] + part1[r][t & 31][lane] + b1r, 0.f);
                // layer 2: cross-multiply + parity butterfly (6 shfls)
                float p = w2own * hv + __shfl_xor(w2oth * hv, 1);
                #pragma unroll
                for (int off = 2; off <= 32; off <<= 1)
                    p += __shfl_xor(p, off);
                if (lane < 2) pbf[j & 1][r * 2 + lane] = p;
            } else {
                part1[r][(t + 16) & 31][lane] = R[j];
            }
            __syncthreads();
            float4 pa = *(const float4*)pbf[j & 1];
            float P0 = pa.x + pa.z;
            float P1 = pa.y + pa.w;

            // ---- controls + dynamics (uniform on all lanes) ----
            float v  = tanh_fast(P0 + b2x);
            float wv = tanh_fast(P1 + b2y);
            S_u += v * v + wv * wv;

            float sn = __sinf(th), cs = __cosf(th);
            float dv = DT * v;
            x  = fmaf(dv, cs, x);
            y  = fmaf(dv, sn, y);
            th = fmaf(DT, wv, th);

            c = conc(x, y);
            S_c += c;

            // ---- push e(t+1) into pending ring: 64 FMAs ----
            #pragma unroll
            for (int k = 0; k < 16; ++k) {
                R[j+1+k] = fmaf(Wp[3*k], x,
                            fmaf(Wp[3*k+1], y,
                             fmaf(Wp[3*k+2], th,
                              fmaf(Wc[k], c, R[j+1+k]))));
            }
        }
        // ---- rotate pending ring by U ----
        #pragma unroll
        for (int i = 0; i < 16; ++i) R[i] = R[i + U];
        #pragma unroll
        for (int i = 16; i < RING; ++i) R[i] = 0.f;
    }

    if (tid == 0) ws[agent] = make_float2(S_c, S_u);
}

__global__ void reduce_kernel(const float2* __restrict__ ws,
                              float* __restrict__ out) {
    const int tid = threadIdx.x;  // 256 threads
    float sc = 0.f, su = 0.f;
    for (int i = tid; i < N_AGENTS; i += 256) {
        float2 v = ws[i];
        sc += v.x;
        su += v.y;
    }
    #pragma unroll
    for (int off = 32; off > 0; off >>= 1) {
        sc += __shfl_xor(sc, off);
        su += __shfl_xor(su, off);
    }
    __shared__ float2 partw[4];
    int wave = tid >> 6;
    if ((tid & 63) == 0) partw[wave] = make_float2(sc, su);
    __syncthreads();
    if (tid == 0) {
        float SC = partw[0].x + partw[1].x + partw[2].x + partw[3].x;
        float SU = partw[0].y + partw[1].y + partw[2].y + partw[3].y;
        const float invNT  = 1.0f / (float)(N_AGENTS * T_STEPS);
        const float invNT2 = 1.0f / (float)(N_AGENTS * T_STEPS * 2);
        out[0] = -SC * invNT + SU * invNT2;
    }
}

extern "C" void kernel_launch(void* const* d_in, const int* in_sizes, int n_in,
                              void* d_out, int out_size, void* d_ws, size_t ws_size,
                              hipStream_t stream) {
    const float* target_pos = (const float*)d_in[0];
    const float* logsigma   = (const float*)d_in[1];
    const float* x_inits    = (const float*)d_in[2];
    const float* W1         = (const float*)d_in[3];
    const float* b1         = (const float*)d_in[4];
    const float* W2         = (const float*)d_in[5];
    const float* b2         = (const float*)d_in[6];
    float2* ws = (float2*)d_ws;

    sim_kernel<<<N_AGENTS, 256, 0, stream>>>(target_pos, logsigma, x_inits,
                                             W1, b1, W2, b2, ws);
    reduce_kernel<<<1, 256, 0, stream>>>(ws, (float*)d_out);
}

// Round 9
// 1126.485 us; speedup vs baseline: 5.4766x; 5.4766x over previous
//
#include <hip/hip_runtime.h>

#define T_STEPS 1000
#define DT 0.1f
#define HIDDEN 128
#define N_AGENTS 1024
#define U 2
#define RING (U + 16)   // pending-accumulator slots (indices 0..U+15)

// tanh(x) = 1 - 2/(exp(2x)+1); exact at +/-inf, ~1e-7 rel error.
__device__ __forceinline__ float tanh_fast(float x) {
    float e = __expf(2.0f * x);
    return 1.0f - 2.0f * __builtin_amdgcn_rcpf(e + 1.0f);
}

// Opaque 16B load: asm results can't be remat'd/sunk into the loop
// (R6-proven: weights stay register-file-resident with zero reload traffic).
__device__ __forceinline__ float4 opaque_load16(const float* p) {
    float4 v;
    asm volatile("global_load_dwordx4 %0, %1, off\n\ts_waitcnt vmcnt(0)"
                 : "=v"(v)
                 : "v"((unsigned long long)(uintptr_t)p)
                 : "memory");
    return v;
}

// Force a wave-uniform float into an SGPR (frees a VGPR; R8 spilled the
// pending ring by ~10-20 regs, so every VGPR counts).
__device__ __forceinline__ float uniformf(float v) {
    return __builtin_bit_cast(float,
        __builtin_amdgcn_readfirstlane(__builtin_bit_cast(int, v)));
}

// PUSH-MODEL, 4 waves/agent. R8 structure (correct: absmax 0.0) with the
// register budget actually respected:
//  - U=2 (ring 18 regs, was 20)
//  - wave-uniform constants in SGPRs via readfirstlane (~11 VGPRs freed)
//  - waves_per_eu(3,4): allocator budget >=170 unified regs, so the ring
//    CANNOT spill (R8: 64 pinned W + ring + working ~135 > 128 hard budget
//    of waves_per_eu(4,4) -> 20 GB scratch traffic).
//
// Wave (r,h): lane owns row 64r+lane, ages 16h..16h+15 (64 weights/lane).
// Pending ring R[18]: at step t push e(t+1)'s contributions into
// R[j+1..j+16] (compile-time indices, U-unrolled), consume R[j].
//   h=0: R[j] + part1 (h=1's partial, written 16 steps ago via LDS) ->
//        bias, relu, layer-2 parity butterfly -> pbf.
//   h=1: ship R[j] (step t+16 partial) to part1[(t+16)&31].
// One barrier/step; slot reuse 16 barriers apart -> race-free.
__global__ __launch_bounds__(256)
__attribute__((amdgpu_waves_per_eu(3, 4)))
void sim_kernel(const float* __restrict__ target_pos,
                const float* __restrict__ logsigma,
                const float* __restrict__ x_inits,
                const float* W1,
                const float* __restrict__ b1,
                const float* __restrict__ W2,
                const float* __restrict__ b2,
                float2* __restrict__ ws) {
    const int agent = blockIdx.x;
    const int tid  = threadIdx.x;   // 0..255
    const int wave = tid >> 6;      // 0..3
    const int lane = tid & 63;
    const int r    = wave >> 1;     // row-group: rows 64r+lane
    const int h    = wave & 1;      // age-half: ages 16h..16h+15
    const int row  = (r << 6) + lane;

    __shared__ float part1[2][32][64];       // h=1 -> h=0, 16-step delay
    __shared__ alignas(16) float pbf[2][4];  // [parity][r*2 + (0:p0|1:p1)]

    const float tx0 = uniformf(target_pos[0]), ty0 = uniformf(target_pos[1]);
    const float tx1 = uniformf(target_pos[2]), ty1 = uniformf(target_pos[3]);
    const float tx2 = uniformf(target_pos[4]), ty2 = uniformf(target_pos[5]);
    const float is0 = uniformf(1.0f / expf(logsigma[0]));
    const float is1 = uniformf(1.0f / expf(logsigma[1]));
    const float is2 = uniformf(1.0f / expf(logsigma[2]));

    // 48 position + 16 conc weights for (row, ages 16h..16h+15).
    float Wp[48], Wc[16];
    {
        const float* rowp = W1 + row * 128;
        #pragma unroll
        for (int i = 0; i < 12; ++i) {
            float4 v = opaque_load16(rowp + 48 * h + 4 * i);
            Wp[4*i] = v.x; Wp[4*i+1] = v.y; Wp[4*i+2] = v.z; Wp[4*i+3] = v.w;
        }
        #pragma unroll
        for (int i = 0; i < 4; ++i) {
            float4 v = opaque_load16(rowp + 96 + 16 * h + 4 * i);
            Wc[4*i] = v.x; Wc[4*i+1] = v.y; Wc[4*i+2] = v.z; Wc[4*i+3] = v.w;
        }
    }
    const float b1r   = b1[row];                      // used by h=0 only
    const float w2own = W2[(lane & 1) * HIDDEN + row];
    const float w2oth = W2[((lane & 1) ^ 1) * HIDDEN + row];
    const float b2x = uniformf(b2[0]), b2y = uniformf(b2[1]);

    float x  = uniformf(x_inits[3 * agent]);
    float y  = uniformf(x_inits[3 * agent + 1]);
    float th = uniformf(x_inits[3 * agent + 2]);

    auto conc = [&](float px, float py) {
        float dx0 = px - tx0, dy0 = py - ty0;
        float dx1 = px - tx1, dy1 = py - ty1;
        float dx2 = px - tx2, dy2 = py - ty2;
        float cc  = is0 * __expf(-(dx0*dx0 + dy0*dy0) * is0);
        cc       += is1 * __expf(-(dx1*dx1 + dy1*dy1) * is1);
        cc       += is2 * __expf(-(dx2*dx2 + dy2*dy2) * is2);
        return cc;
    };

    float c = conc(x, y);

    // Seed: history pre-filled with e(0). R[k] = sum_{j=k..15} Wloc[j].e(0).
    float R[RING];
    #pragma unroll
    for (int i = 16; i < RING; ++i) R[i] = 0.f;
    {
        float acc = 0.f;
        #pragma unroll
        for (int k = 15; k >= 0; --k) {
            acc = fmaf(Wp[3*k], x,
                   fmaf(Wp[3*k+1], y,
                    fmaf(Wp[3*k+2], th,
                     fmaf(Wc[k], c, acc))));
            R[k] = acc;
        }
    }
    // h=1 partials for steps 0..15 are all the full e(0) sum = R[0].
    if (h == 1) {
        #pragma unroll
        for (int s = 0; s < 16; ++s) part1[r][s][lane] = R[0];
    }
    __syncthreads();

    float S_c = 0.f, S_u = 0.f;
    int t = 0;

    #pragma unroll 1
    for (int tt = 0; tt < T_STEPS / U; ++tt) {
        #pragma unroll
        for (int j = 0; j < U; ++j, ++t) {
            // ---- consume / ship (wave-uniform branch, no divergence) ----
            if (h == 0) {
                float hv = fmaxf(R[j] + part1[r][t & 31][lane] + b1r, 0.f);
                // layer 2: cross-multiply + parity butterfly (6 shfls)
                float p = w2own * hv + __shfl_xor(w2oth * hv, 1);
                #pragma unroll
                for (int off = 2; off <= 32; off <<= 1)
                    p += __shfl_xor(p, off);
                if (lane < 2) pbf[j & 1][r * 2 + lane] = p;
            } else {
                part1[r][(t + 16) & 31][lane] = R[j];
            }
            __syncthreads();
            float4 pa = *(const float4*)pbf[j & 1];
            float P0 = pa.x + pa.z;
            float P1 = pa.y + pa.w;

            // ---- controls + dynamics (uniform on all lanes) ----
            float v  = tanh_fast(P0 + b2x);
            float wv = tanh_fast(P1 + b2y);
            S_u += v * v + wv * wv;

            float sn = __sinf(th), cs = __cosf(th);
            float dv = DT * v;
            x  = fmaf(dv, cs, x);
            y  = fmaf(dv, sn, y);
            th = fmaf(DT, wv, th);

            c = conc(x, y);
            S_c += c;

            // ---- push e(t+1) into pending ring: 64 FMAs ----
            #pragma unroll
            for (int k = 0; k < 16; ++k) {
                R[j+1+k] = fmaf(Wp[3*k], x,
                            fmaf(Wp[3*k+1], y,
                             fmaf(Wp[3*k+2], th,
                              fmaf(Wc[k], c, R[j+1+k]))));
            }
        }
        // ---- rotate pending ring by U ----
        #pragma unroll
        for (int i = 0; i < 16; ++i) R[i] = R[i + U];
        #pragma unroll
        for (int i = 16; i < RING; ++i) R[i] = 0.f;
    }

    if (tid == 0) ws[agent] = make_float2(S_c, S_u);
}

__global__ void reduce_kernel(const float2* __restrict__ ws,
                              float* __restrict__ out) {
    const int tid = threadIdx.x;  // 256 threads
    float sc = 0.f, su = 0.f;
    for (int i = tid; i < N_AGENTS; i += 256) {
        float2 v = ws[i];
        sc += v.x;
        su += v.y;
    }
    #pragma unroll
    for (int off = 32; off > 0; off >>= 1) {
        sc += __shfl_xor(sc, off);
        su += __shfl_xor(su, off);
    }
    __shared__ float2 partw[4];
    int wave = tid >> 6;
    if ((tid & 63) == 0) partw[wave] = make_float2(sc, su);
    __syncthreads();
    if (tid == 0) {
        float SC = partw[0].x + partw[1].x + partw[2].x + partw[3].x;
        float SU = partw[0].y + partw[1].y + partw[2].y + partw[3].y;
        const float invNT  = 1.0f / (float)(N_AGENTS * T_STEPS);
        const float invNT2 = 1.0f / (float)(N_AGENTS * T_STEPS * 2);
        out[0] = -SC * invNT + SU * invNT2;
    }
}

extern "C" void kernel_launch(void* const* d_in, const int* in_sizes, int n_in,
                              void* d_out, int out_size, void* d_ws, size_t ws_size,
                              hipStream_t stream) {
    const float* target_pos = (const float*)d_in[0];
    const float* logsigma   = (const float*)d_in[1];
    const float* x_inits    = (const float*)d_in[2];
    const float* W1         = (const float*)d_in[3];
    const float* b1         = (const float*)d_in[4];
    const float* W2         = (const float*)d_in[5];
    const float* b2         = (const float*)d_in[6];
    float2* ws = (float2*)d_ws;

    sim_kernel<<<N_AGENTS, 256, 0, stream>>>(target_pos, logsigma, x_inits,
                                             W1, b1, W2, b2, ws);
    reduce_kernel<<<1, 256, 0, stream>>>(ws, (float*)d_out);
}